// Round 2
// baseline (999.251 us; speedup 1.0000x reference)
//
#include <hip/hip_runtime.h>

// Self-attention B=8 S=2048 D=512. Input dtype (fp32 vs bf16) detected on
// device; all compute via bf16 split-MFMA (verified 16x16x32_bf16 layouts),
// fp32 logits + softmax, bf16 P, output written in the detected dtype.

typedef unsigned short u16;
typedef unsigned int u32;
typedef __attribute__((ext_vector_type(8))) __bf16 bf16x8;
typedef __attribute__((ext_vector_type(4))) float f32x4;

#define S_LEN 2048
#define D_DIM 512
#define B_N 8
#define TILE_K 32
#define LDS_LD 40   // 32 + 8 pad

__device__ __forceinline__ u16 f2bf(float f) {
    u32 u = __float_as_uint(f);
    u32 r = u + 0x7FFFu + ((u >> 16) & 1u);   // RNE
    return (u16)(r >> 16);
}
__device__ __forceinline__ float bf2f(u16 h) {
    return __uint_as_float((u32)h << 16);
}
__device__ __forceinline__ void split2(float f, u16& h, u16& l) {
    h = f2bf(f);
    l = f2bf(f - bf2f(h));
}

// ---- dtype detector: even u16s of an fp32 buffer are uniform mantissa bits;
// of a bf16 buffer they are sane bf16 values. One wave votes. ----
__global__ void detect_k(const u16* __restrict__ x, int* __restrict__ flag)
{
    int t = threadIdx.x;           // 64 threads
    u16 u = x[2 * t];
    int e = (u >> 7) & 0xFF;
    int sane = (e == 0) || (e >= 110 && e <= 140);
    unsigned long long b = __ballot(sane);
    if (t == 0) *flag = (__popcll(b) >= 32) ? 1 : 0;   // 1 = bf16 inputs
}

// ---- projection GEMM: C = splitbf16(x)@splitbf16(W) + bias, 3-term.
// x:[M,512] W:[512,512] row-major, dtype per flag. SPLITOUT: write (hi,lo).
template <bool SPLITOUT>
__global__ __launch_bounds__(256) void proj_gemm(
    const void* __restrict__ Xv, const void* __restrict__ Wm,
    const void* __restrict__ biasv, u16* __restrict__ Ch, u16* __restrict__ Cl,
    const int* __restrict__ flagp)
{
    const int isbf = *flagp;
    const int tid = threadIdx.x;
    const int lane = tid & 63, wav = tid >> 6;
    const int l15 = lane & 15, quad = lane >> 4;
    const int m0 = blockIdx.y * 128, n0 = blockIdx.x * 128;
    const int bm = (wav >> 1) * 64, bn = (wav & 1) * 64;

    __shared__ u16 Ah[128 * LDS_LD], Al[128 * LDS_LD];
    __shared__ u16 Bh[128 * LDS_LD], Bl[128 * LDS_LD];

    f32x4 acc[4][4];
#pragma unroll
    for (int i = 0; i < 4; i++)
#pragma unroll
        for (int j = 0; j < 4; j++) acc[i][j] = (f32x4){0.f, 0.f, 0.f, 0.f};

    for (int k0 = 0; k0 < 512; k0 += TILE_K) {
        // A tile 128x32, 4 elems/chunk
        for (int cch = tid; cch < 1024; cch += 256) {
            int row = cch >> 3, kc = (cch & 7) * 4;
            size_t gi = (size_t)(m0 + row) * 512 + k0 + kc;
            float f[4];
            if (isbf) {
                ushort4 uu = *(const ushort4*)((const u16*)Xv + gi);
                f[0] = bf2f(uu.x); f[1] = bf2f(uu.y); f[2] = bf2f(uu.z); f[3] = bf2f(uu.w);
            } else {
                float4 ff = *(const float4*)((const float*)Xv + gi);
                f[0] = ff.x; f[1] = ff.y; f[2] = ff.z; f[3] = ff.w;
            }
            int o = row * LDS_LD + kc;
#pragma unroll
            for (int i = 0; i < 4; i++) { u16 h, l; split2(f[i], h, l); Ah[o + i] = h; Al[o + i] = l; }
        }
        // B tile: W[k0+kk][n0+nn] -> n-major
        for (int e = tid; e < 4096; e += 256) {
            int kk = e >> 7, nn = e & 127;
            size_t gi = (size_t)(k0 + kk) * 512 + n0 + nn;
            float f = isbf ? bf2f(((const u16*)Wm)[gi]) : ((const float*)Wm)[gi];
            u16 h, l; split2(f, h, l);
            Bh[nn * LDS_LD + kk] = h; Bl[nn * LDS_LD + kk] = l;
        }
        __syncthreads();

        bf16x8 ah[4], al[4], bh[4], bl[4];
#pragma unroll
        for (int i = 0; i < 4; i++) {
            int ro = (bm + i * 16 + l15) * LDS_LD + quad * 8;
            ah[i] = *(const bf16x8*)&Ah[ro];
            al[i] = *(const bf16x8*)&Al[ro];
        }
#pragma unroll
        for (int j = 0; j < 4; j++) {
            int ro = (bn + j * 16 + l15) * LDS_LD + quad * 8;
            bh[j] = *(const bf16x8*)&Bh[ro];
            bl[j] = *(const bf16x8*)&Bl[ro];
        }
#pragma unroll
        for (int i = 0; i < 4; i++)
#pragma unroll
            for (int j = 0; j < 4; j++) {
                acc[i][j] = __builtin_amdgcn_mfma_f32_16x16x32_bf16(ah[i], bh[j], acc[i][j], 0, 0, 0);
                acc[i][j] = __builtin_amdgcn_mfma_f32_16x16x32_bf16(al[i], bh[j], acc[i][j], 0, 0, 0);
                acc[i][j] = __builtin_amdgcn_mfma_f32_16x16x32_bf16(ah[i], bl[j], acc[i][j], 0, 0, 0);
            }
        __syncthreads();
    }

    // epilogue: C/D layout col=lane&15, row=quad*4+reg
#pragma unroll
    for (int i = 0; i < 4; i++)
#pragma unroll
        for (int j = 0; j < 4; j++) {
            int col = n0 + bn + j * 16 + l15;
            float badd = isbf ? bf2f(((const u16*)biasv)[col]) : ((const float*)biasv)[col];
#pragma unroll
            for (int r = 0; r < 4; r++) {
                int row = m0 + bm + i * 16 + quad * 4 + r;
                float v = acc[i][j][r] + badd;
                size_t idx = (size_t)row * 512 + col;
                if (SPLITOUT) { u16 h, l; split2(v, h, l); Ch[idx] = h; Cl[idx] = l; }
                else Ch[idx] = f2bf(v);
            }
        }
}

// ---- generic multi-term bf16 GEMM. BT: B is [N,K]. OUT 0=fp32, 1=flag-dtyped.
template <bool BT, int OUT>
__global__ __launch_bounds__(256) void gemm_k(
    const u16* __restrict__ A0, const u16* __restrict__ A1, const u16* __restrict__ A2,
    const u16* __restrict__ B0, const u16* __restrict__ B1, const u16* __restrict__ B2,
    int nt, void* __restrict__ Cp, const int* __restrict__ flagp,
    int M, int N, int K, int lda, int ldb, int ldc,
    long sA, long sB, long sC, long cbase)
{
    const int isbf = (OUT == 1) ? *flagp : 0;
    const int tid = threadIdx.x;
    const int lane = tid & 63, wav = tid >> 6;
    const int l15 = lane & 15, quad = lane >> 4;
    const int m0 = blockIdx.y * 128, n0 = blockIdx.x * 128;
    const int bm = (wav >> 1) * 64, bn = (wav & 1) * 64;

    __shared__ u16 As[128 * LDS_LD];
    __shared__ u16 Bs[128 * LDS_LD];

    f32x4 acc[4][4];
#pragma unroll
    for (int i = 0; i < 4; i++)
#pragma unroll
        for (int j = 0; j < 4; j++) acc[i][j] = (f32x4){0.f, 0.f, 0.f, 0.f};

    for (int t = 0; t < nt; t++) {
        const u16* A = (t == 0 ? A0 : t == 1 ? A1 : A2) + (size_t)blockIdx.z * sA;
        const u16* B = (t == 0 ? B0 : t == 1 ? B1 : B2) + (size_t)blockIdx.z * sB;
        for (int k0 = 0; k0 < K; k0 += TILE_K) {
            for (int c = tid; c < 512; c += 256) {
                int row = c >> 2, kc = (c & 3) << 3;
                *(uint4*)&As[row * LDS_LD + kc] =
                    *(const uint4*)&A[(size_t)(m0 + row) * lda + k0 + kc];
            }
            if (BT) {
                for (int c = tid; c < 512; c += 256) {
                    int row = c >> 2, kc = (c & 3) << 3;
                    *(uint4*)&Bs[row * LDS_LD + kc] =
                        *(const uint4*)&B[(size_t)(n0 + row) * ldb + k0 + kc];
                }
            } else {
                for (int e = tid; e < 4096; e += 256) {
                    int kk = e >> 7, nn = e & 127;
                    Bs[nn * LDS_LD + kk] = B[(size_t)(k0 + kk) * ldb + n0 + nn];
                }
            }
            __syncthreads();

            bf16x8 af[4], bfr[4];
#pragma unroll
            for (int i = 0; i < 4; i++)
                af[i] = *(const bf16x8*)&As[(bm + i * 16 + l15) * LDS_LD + quad * 8];
#pragma unroll
            for (int j = 0; j < 4; j++)
                bfr[j] = *(const bf16x8*)&Bs[(bn + j * 16 + l15) * LDS_LD + quad * 8];
#pragma unroll
            for (int i = 0; i < 4; i++)
#pragma unroll
                for (int j = 0; j < 4; j++)
                    acc[i][j] = __builtin_amdgcn_mfma_f32_16x16x32_bf16(af[i], bfr[j], acc[i][j], 0, 0, 0);
            __syncthreads();
        }
    }

    float* Cf = (float*)Cp;
    u16*   Cb = (u16*)Cp;
    const long coff = cbase + (long)blockIdx.z * sC;
#pragma unroll
    for (int i = 0; i < 4; i++)
#pragma unroll
        for (int j = 0; j < 4; j++) {
            int col = n0 + bn + j * 16 + l15;
#pragma unroll
            for (int r = 0; r < 4; r++) {
                int row = m0 + bm + i * 16 + quad * 4 + r;
                float v = acc[i][j][r];
                size_t idx = (size_t)(coff + (long)row * ldc + col);
                if (OUT == 0) Cf[idx] = v;
                else { if (isbf) Cb[idx] = f2bf(v); else Cf[idx] = v; }
            }
        }
}

// ---- softmax: fp32 logits -> bf16 P in place over first half of row bytes ----
__global__ __launch_bounds__(256) void softmax_k(float* __restrict__ sc)
{
    float* srow = sc + (size_t)blockIdx.x * S_LEN;
    const int tid = threadIdx.x;

    float v[8];
#pragma unroll
    for (int j = 0; j < 8; j++) v[j] = srow[tid + 256 * j];

    float m = v[0];
#pragma unroll
    for (int j = 1; j < 8; j++) m = fmaxf(m, v[j]);
#pragma unroll
    for (int off = 32; off > 0; off >>= 1) m = fmaxf(m, __shfl_down(m, off));

    __shared__ float redm[4], reds[4];
    if ((tid & 63) == 0) redm[tid >> 6] = m;
    __syncthreads();
    m = fmaxf(fmaxf(redm[0], redm[1]), fmaxf(redm[2], redm[3]));

    float e[8];
    float s = 0.f;
#pragma unroll
    for (int j = 0; j < 8; j++) { e[j] = __expf(v[j] - m); s += e[j]; }
#pragma unroll
    for (int off = 32; off > 0; off >>= 1) s += __shfl_down(s, off);
    if ((tid & 63) == 0) reds[tid >> 6] = s;
    __syncthreads();
    s = reds[0] + reds[1] + reds[2] + reds[3];

    const float inv = 1.0f / s;
    u16* pb = (u16*)srow;
#pragma unroll
    for (int j = 0; j < 8; j++) pb[tid + 256 * j] = f2bf(e[j] * inv);
}

extern "C" void kernel_launch(void* const* d_in, const int* in_sizes, int n_in,
                              void* d_out, int out_size, void* d_ws, size_t ws_size,
                              hipStream_t stream)
{
    const void* x  = d_in[0];
    const void* Wq = d_in[1]; const void* bq = d_in[2];
    const void* Wk = d_in[3]; const void* bk = d_in[4];
    const void* Wv = d_in[5]; const void* bv = d_in[6];

    const int S = S_LEN, D = D_DIM;
    const int M = B_N * S;                      // 16384
    const size_t PER = (size_t)M * D;           // 8,388,608 elems

    int* flag = (int*)d_ws;
    u16* qh = (u16*)((char*)d_ws + 16);
    u16* ql = qh + PER;
    u16* kh = ql + PER;
    u16* kl = kh + PER;
    u16* vh = kl + PER;
    float* sc = (float*)(vh + PER);             // arena @ byte 16 + 83,886,080

    const size_t fixed = 16 + 5 * PER * 2;
    const size_t avail = ws_size > fixed ? ws_size - fixed : 0;
    const size_t perb = (size_t)S * S * 4;      // 16,777,216 B per batch of scores
    int c = avail >= 8 * perb ? 8 : avail >= 4 * perb ? 4 : avail >= 2 * perb ? 2 : 1;

    dim3 blk(256);

    detect_k<<<1, 64, 0, stream>>>((const u16*)x, flag);

    proj_gemm<true><<<dim3(4, 128), blk, 0, stream>>>(x, Wq, bq, qh, ql, flag);
    proj_gemm<true><<<dim3(4, 128), blk, 0, stream>>>(x, Wk, bk, kh, kl, flag);
    proj_gemm<false><<<dim3(4, 128), blk, 0, stream>>>(x, Wv, bv, vh, nullptr, flag);

    const long SD = (long)S * D;
    for (int cb = 0; cb < B_N; cb += c) {
        const size_t off = (size_t)cb * SD;
        // scores = qh*kh + ql*kh + qh*kl  (fp32, chunk of c batches)
        gemm_k<true, 0><<<dim3(16, 16, c), blk, 0, stream>>>(
            qh + off, ql + off, qh + off, kh + off, kh + off, kl + off, 3,
            sc, flag, S, S, D, D, D, S, SD, SD, (long)S * S, 0);
        softmax_k<<<c * S, blk, 0, stream>>>(sc);
        // out = P @ v  (P bf16 over fp32 rows, lda = 2S)
        gemm_k<false, 1><<<dim3(4, 16, c), blk, 0, stream>>>(
            (const u16*)sc, nullptr, nullptr, vh + off, nullptr, nullptr, 1,
            d_out, flag, S, D, S, 2 * S, D, D,
            2ll * S * S, SD, SD, (long)cb * SD);
    }
}

// Round 3
// 452.398 us; speedup vs baseline: 2.2088x; 2.2088x over previous
//
#include <hip/hip_runtime.h>

// Self-attention B=8 S=2048 D=512, fp32-vs-bf16 input auto-detect.
// All GEMMs: m97-style 128x128 tile, BK=32, global_load_lds dwordx4,
// XOR-swizzled LDS (no padding, conflict-free), bf16 split-MFMA numerics
// identical to the round-2 passing kernel.

typedef unsigned short u16;
typedef unsigned int u32;
typedef __attribute__((ext_vector_type(8))) __bf16 bf16x8;
typedef __attribute__((ext_vector_type(4))) float f32x4;

#define S_LEN 2048
#define D_DIM 512
#define B_N 8

__device__ __forceinline__ u16 f2bf(float f) {
    u32 u = __float_as_uint(f);
    u32 r = u + 0x7FFFu + ((u >> 16) & 1u);   // RNE
    return (u16)(r >> 16);
}
__device__ __forceinline__ float bf2f(u16 h) {
    return __uint_as_float((u32)h << 16);
}
__device__ __forceinline__ void split2(float f, u16& h, u16& l) {
    h = f2bf(f);
    l = f2bf(f - bf2f(h));
}
__device__ __forceinline__ void gl16(const u16* g, u16* l) {
    __builtin_amdgcn_global_load_lds(
        (const __attribute__((address_space(1))) void*)g,
        (__attribute__((address_space(3))) void*)l, 16, 0, 0);
}

// ---- dtype detector ----
__global__ void detect_k(const u16* __restrict__ x, int* __restrict__ flag)
{
    int t = threadIdx.x;
    u16 u = x[2 * t];
    int e = (u >> 7) & 0xFF;
    int sane = (e == 0) || (e >= 110 && e <= 140);
    unsigned long long b = __ballot(sane);
    if (t == 0) *flag = (__popcll(b) >= 32) ? 1 : 0;
}

// ---- split x (fp32 or bf16) into hi/lo bf16 ----
__global__ __launch_bounds__(256) void split_x(
    const void* __restrict__ X, u16* __restrict__ xh, u16* __restrict__ xl,
    const int* __restrict__ flagp)
{
    const size_t i4 = ((size_t)blockIdx.x * 256 + threadIdx.x) * 4;
    float f[4];
    if (*flagp) {
        ushort4 u = *(const ushort4*)((const u16*)X + i4);
        f[0] = bf2f(u.x); f[1] = bf2f(u.y); f[2] = bf2f(u.z); f[3] = bf2f(u.w);
    } else {
        float4 ff = *(const float4*)((const float*)X + i4);
        f[0] = ff.x; f[1] = ff.y; f[2] = ff.z; f[3] = ff.w;
    }
    ushort4 h, l;
    split2(f[0], h.x, l.x); split2(f[1], h.y, l.y);
    split2(f[2], h.z, l.z); split2(f[3], h.w, l.w);
    *(ushort4*)(xh + i4) = h;
    *(ushort4*)(xl + i4) = l;
}

// ---- pack W^T concat (q|k|v) hi/lo: WT[n in 0..1535][k in 0..511] ----
__global__ __launch_bounds__(256) void pack_w(
    const void* __restrict__ Wq, const void* __restrict__ Wk, const void* __restrict__ Wv,
    u16* __restrict__ WTh, u16* __restrict__ WTl, const int* __restrict__ flagp)
{
    const int k = blockIdx.x;                       // 0..511
    const int n = blockIdx.y * 256 + threadIdx.x;   // 0..1535
    const void* W = n < 512 ? Wq : n < 1024 ? Wk : Wv;
    const int nc = n & 511;
    float f = *flagp ? bf2f(((const u16*)W)[(size_t)k * 512 + nc])
                     : ((const float*)W)[(size_t)k * 512 + nc];
    u16 h, l; split2(f, h, l);
    WTh[(size_t)n * 512 + k] = h;
    WTl[(size_t)n * 512 + k] = l;
}

__global__ void pack_bias(
    const void* __restrict__ bq, const void* __restrict__ bk, const void* __restrict__ bv,
    float* __restrict__ bcat, const int* __restrict__ flagp)
{
    const int t = blockIdx.x * 256 + threadIdx.x;   // 0..1535
    const void* b = t < 512 ? bq : t < 1024 ? bk : bv;
    const int i = t & 511;
    bcat[t] = *flagp ? bf2f(((const u16*)b)[i]) : ((const float*)b)[i];
}

// ---- unified BT-GEMM: C[M,N] = sum_t A_t[M,K] * B_t[N,K]^T ----
// EPI 0: fp32 C. EPI 1: flag-dtyped C. EPI 2: proj (split q/k + vT + bias).
template <int NT, int EPI>
__global__ __launch_bounds__(256) void gemm_bt(
    const u16* __restrict__ A0, const u16* __restrict__ A1, const u16* __restrict__ A2,
    const u16* __restrict__ B0, const u16* __restrict__ B1, const u16* __restrict__ B2,
    void* __restrict__ Cp, const float* __restrict__ biasf,
    u16* __restrict__ O1h, u16* __restrict__ O1l,
    u16* __restrict__ O2h, u16* __restrict__ O2l,
    u16* __restrict__ O3t, const int* __restrict__ flagp,
    int K, int lda, int ldb, int ldc,
    long sA, long sB, long sC, long cbase)
{
    const int tid = threadIdx.x;
    const int lane = tid & 63, wav = tid >> 6;
    const int l15 = lane & 15, quad = lane >> 4;
    const int m0 = blockIdx.y * 128, n0 = blockIdx.x * 128;
    const int bm = (wav >> 1) * 64, bn = (wav & 1) * 64;

    __shared__ __align__(16) u16 As[4096];   // 128 rows x 32, chunk-swizzled
    __shared__ __align__(16) u16 Bs[4096];

    // staging map: linear chunk i -> row r=i>>2, slot s=i&3 holds global
    // chunk c = s ^ ((r>>1)&3). Round 0: i = tid; round 1: i = 256+tid.
    const int rr = tid >> 2;
    const int cc = ((tid & 3) ^ ((rr >> 1) & 3)) * 8;
    const size_t aoff0 = (size_t)(m0 + rr) * lda + cc;
    const size_t aoff1 = aoff0 + (size_t)64 * lda;
    const size_t boff0 = (size_t)(n0 + rr) * ldb + cc;
    const size_t boff1 = boff0 + (size_t)64 * ldb;
    const int swz = ((quad ^ ((l15 >> 1) & 3))) * 8;

    f32x4 acc[4][4];
#pragma unroll
    for (int i = 0; i < 4; i++)
#pragma unroll
        for (int j = 0; j < 4; j++) acc[i][j] = (f32x4){0.f, 0.f, 0.f, 0.f};

#pragma unroll 1
    for (int t = 0; t < NT; t++) {
        const u16* A = (t == 0 ? A0 : t == 1 ? A1 : A2) + (size_t)blockIdx.z * sA;
        const u16* B = (t == 0 ? B0 : t == 1 ? B1 : B2) + (size_t)blockIdx.z * sB;
        for (int k0 = 0; k0 < K; k0 += 32) {
            gl16(A + aoff0 + k0, As + wav * 512);
            gl16(A + aoff1 + k0, As + 2048 + wav * 512);
            gl16(B + boff0 + k0, Bs + wav * 512);
            gl16(B + boff1 + k0, Bs + 2048 + wav * 512);
            __syncthreads();

            bf16x8 af[4], bb[4];
#pragma unroll
            for (int i = 0; i < 4; i++)
                af[i] = *(const bf16x8*)&As[(bm + i * 16 + l15) * 32 + swz];
#pragma unroll
            for (int j = 0; j < 4; j++)
                bb[j] = *(const bf16x8*)&Bs[(bn + j * 16 + l15) * 32 + swz];
#pragma unroll
            for (int i = 0; i < 4; i++)
#pragma unroll
                for (int j = 0; j < 4; j++)
                    acc[i][j] = __builtin_amdgcn_mfma_f32_16x16x32_bf16(
                        af[i], bb[j], acc[i][j], 0, 0, 0);
            __syncthreads();
        }
    }

    // ---- epilogue (C/D layout: col = lane&15, row = quad*4 + reg) ----
    if (EPI == 2) {
        const int mode = blockIdx.x >> 2;   // 0=q 1=k 2=v (128 | 512-boundaries align)
#pragma unroll
        for (int i = 0; i < 4; i++)
#pragma unroll
            for (int j = 0; j < 4; j++) {
                const int gcol = n0 + bn + j * 16 + l15;
                const int lcol = gcol & 511;
                const float badd = biasf[gcol];
#pragma unroll
                for (int r = 0; r < 4; r++) {
                    const int row = m0 + bm + i * 16 + quad * 4 + r;
                    const float v = acc[i][j][r] + badd;
                    if (mode == 0) {
                        u16 h, l; split2(v, h, l);
                        O1h[(size_t)row * 512 + lcol] = h;
                        O1l[(size_t)row * 512 + lcol] = l;
                    } else if (mode == 1) {
                        u16 h, l; split2(v, h, l);
                        O2h[(size_t)row * 512 + lcol] = h;
                        O2l[(size_t)row * 512 + lcol] = l;
                    } else {
                        O3t[(size_t)lcol * 16384 + row] = f2bf(v);
                    }
                }
            }
    } else {
        const int isbf = (EPI == 1) ? *flagp : 0;
        float* Cf = (float*)Cp;
        u16* Cb = (u16*)Cp;
        const long coff = cbase + (long)blockIdx.z * sC;
#pragma unroll
        for (int i = 0; i < 4; i++)
#pragma unroll
            for (int j = 0; j < 4; j++) {
                const int col = n0 + bn + j * 16 + l15;
#pragma unroll
                for (int r = 0; r < 4; r++) {
                    const int row = m0 + bm + i * 16 + quad * 4 + r;
                    const float v = acc[i][j][r];
                    const size_t idx = (size_t)(coff + (long)row * ldc + col);
                    if (EPI == 0) Cf[idx] = v;
                    else { if (isbf) Cb[idx] = f2bf(v); else Cf[idx] = v; }
                }
            }
    }
}

// ---- softmax: fp32 row -> bf16 P in place (first half of row bytes) ----
__global__ __launch_bounds__(256) void softmax_k(float* __restrict__ sc)
{
    float* srow = sc + (size_t)blockIdx.x * S_LEN;
    const int tid = threadIdx.x;

    float4 a = ((const float4*)srow)[tid];
    float4 b = ((const float4*)srow)[256 + tid];

    float m = fmaxf(fmaxf(fmaxf(a.x, a.y), fmaxf(a.z, a.w)),
                    fmaxf(fmaxf(b.x, b.y), fmaxf(b.z, b.w)));
#pragma unroll
    for (int off = 32; off > 0; off >>= 1) m = fmaxf(m, __shfl_down(m, off));

    __shared__ float redm[4], reds[4];
    if ((tid & 63) == 0) redm[tid >> 6] = m;
    __syncthreads();
    m = fmaxf(fmaxf(redm[0], redm[1]), fmaxf(redm[2], redm[3]));

    a.x = __expf(a.x - m); a.y = __expf(a.y - m);
    a.z = __expf(a.z - m); a.w = __expf(a.w - m);
    b.x = __expf(b.x - m); b.y = __expf(b.y - m);
    b.z = __expf(b.z - m); b.w = __expf(b.w - m);
    float s = a.x + a.y + a.z + a.w + b.x + b.y + b.z + b.w;
#pragma unroll
    for (int off = 32; off > 0; off >>= 1) s += __shfl_down(s, off);
    if ((tid & 63) == 0) reds[tid >> 6] = s;
    __syncthreads();
    s = reds[0] + reds[1] + reds[2] + reds[3];

    const float inv = 1.0f / s;
    ushort4 pa, pb;
    pa.x = f2bf(a.x * inv); pa.y = f2bf(a.y * inv);
    pa.z = f2bf(a.z * inv); pa.w = f2bf(a.w * inv);
    pb.x = f2bf(b.x * inv); pb.y = f2bf(b.y * inv);
    pb.z = f2bf(b.z * inv); pb.w = f2bf(b.w * inv);
    ((ushort4*)srow)[tid] = pa;
    ((ushort4*)srow)[256 + tid] = pb;
}

extern "C" void kernel_launch(void* const* d_in, const int* in_sizes, int n_in,
                              void* d_out, int out_size, void* d_ws, size_t ws_size,
                              hipStream_t stream)
{
    const void* x  = d_in[0];
    const void* Wq = d_in[1]; const void* bq = d_in[2];
    const void* Wk = d_in[3]; const void* bk = d_in[4];
    const void* Wv = d_in[5]; const void* bv = d_in[6];

    const int S = S_LEN, D = D_DIM;
    const long SD = (long)S * D;                // 1,048,576

    char* w = (char*)d_ws;
    int*   flag = (int*)w;                      // 256 B
    u16*   WTh  = (u16*)(w + 256);              // 1536*512*2 = 1,572,864
    u16*   WTl  = WTh + 786432;
    float* bcat = (float*)(WTl + 786432);       // 6144 B (pad to 6400)
    u16*   qh   = (u16*)(w + 3152128);          // 5 x 16,777,216
    u16*   ql   = qh + 8388608;
    u16*   kh   = ql + 8388608;
    u16*   kl   = kh + 8388608;
    u16*   vT   = kl + 8388608;                 // [512][16384]
    u16*   xh   = vT + 8388608;                 // @ 87,038,208
    u16*   xl   = xh + 8388608;
    float* scA  = (float*)xh;                   // scores arena reuses x-split region

    const size_t avail = ws_size > 87038208ull ? ws_size - 87038208ull : 0;
    const size_t perb = (size_t)S * S * 4;
    const int c = avail >= 8 * perb ? 8 : avail >= 4 * perb ? 4 : avail >= 2 * perb ? 2 : 1;

    dim3 blk(256);

    detect_k<<<1, 64, 0, stream>>>((const u16*)x, flag);
    split_x<<<8192, blk, 0, stream>>>(x, xh, xl, flag);
    pack_w<<<dim3(512, 6), blk, 0, stream>>>(Wq, Wk, Wv, WTh, WTl, flag);
    pack_bias<<<6, blk, 0, stream>>>(bq, bk, bv, bcat, flag);

    // fused q|k|v projection: [16384,512] x [512,1536], 3-term split
    gemm_bt<3, 2><<<dim3(12, 128, 1), blk, 0, stream>>>(
        xh, xl, xh, WTh, WTh, WTl, nullptr, bcat,
        qh, ql, kh, kl, vT, flag, 512, 512, 512, 0, 0, 0, 0, 0);

    for (int cb = 0; cb < B_N; cb += c) {
        const size_t off = (size_t)cb * SD;
        // scores = qh kh^T + ql kh^T + qh kl^T  (fp32)
        gemm_bt<3, 0><<<dim3(16, 16, c), blk, 0, stream>>>(
            qh + off, ql + off, qh + off, kh + off, kh + off, kl + off,
            scA, nullptr, nullptr, nullptr, nullptr, nullptr, nullptr, flag,
            512, 512, 512, S, SD, SD, (long)S * S, 0);
        softmax_k<<<c * S, blk, 0, stream>>>(scA);
        // out = P @ v  via vT: A = P rows (lda = 2S u16), B = vT rows
        gemm_bt<1, 1><<<dim3(4, 16, c), blk, 0, stream>>>(
            (const u16*)scA, nullptr, nullptr, vT + (size_t)cb * S, nullptr, nullptr,
            d_out, nullptr, nullptr, nullptr, nullptr, nullptr, nullptr, flag,
            S, 2 * S, B_N * S, D, 2ll * S * S, S, SD, (long)cb * SD);
    }
}

// Round 4
// 419.295 us; speedup vs baseline: 2.3832x; 1.0789x over previous
//
#include <hip/hip_runtime.h>

// Self-attention B=8 S=2048 D=512, fp32-vs-bf16 input auto-detect.
// R4: fused 3-term split GEMM (one staging pass feeds hh+lh+hl),
// 32x32x16 MFMA, BK=32 (split3) / BK=64 (PV), XOR-swizzled LDS.

typedef unsigned short u16;
typedef unsigned int u32;
typedef __attribute__((ext_vector_type(8))) __bf16 bf16x8;
typedef __attribute__((ext_vector_type(16))) float f32x16;

#define S_LEN 2048
#define D_DIM 512
#define B_N 8

__device__ __forceinline__ u16 f2bf(float f) {
    u32 u = __float_as_uint(f);
    u32 r = u + 0x7FFFu + ((u >> 16) & 1u);   // RNE
    return (u16)(r >> 16);
}
__device__ __forceinline__ float bf2f(u16 h) {
    return __uint_as_float((u32)h << 16);
}
__device__ __forceinline__ void split2(float f, u16& h, u16& l) {
    h = f2bf(f);
    l = f2bf(f - bf2f(h));
}
__device__ __forceinline__ void gl16(const u16* g, u16* l) {
    __builtin_amdgcn_global_load_lds(
        (const __attribute__((address_space(1))) void*)g,
        (__attribute__((address_space(3))) void*)l, 16, 0, 0);
}
__device__ __forceinline__ f32x16 mfma32(bf16x8 a, bf16x8 b, f32x16 c) {
    return __builtin_amdgcn_mfma_f32_32x32x16_bf16(a, b, c, 0, 0, 0);
}

// ---- dtype detector ----
__global__ void detect_k(const u16* __restrict__ x, int* __restrict__ flag)
{
    int t = threadIdx.x;
    u16 u = x[2 * t];
    int e = (u >> 7) & 0xFF;
    int sane = (e == 0) || (e >= 110 && e <= 140);
    unsigned long long b = __ballot(sane);
    if (t == 0) *flag = (__popcll(b) >= 32) ? 1 : 0;
}

// ---- split x into hi/lo bf16 ----
__global__ __launch_bounds__(256) void split_x(
    const void* __restrict__ X, u16* __restrict__ xh, u16* __restrict__ xl,
    const int* __restrict__ flagp)
{
    const size_t i4 = ((size_t)blockIdx.x * 256 + threadIdx.x) * 4;
    float f[4];
    if (*flagp) {
        ushort4 u = *(const ushort4*)((const u16*)X + i4);
        f[0] = bf2f(u.x); f[1] = bf2f(u.y); f[2] = bf2f(u.z); f[3] = bf2f(u.w);
    } else {
        float4 ff = *(const float4*)((const float*)X + i4);
        f[0] = ff.x; f[1] = ff.y; f[2] = ff.z; f[3] = ff.w;
    }
    ushort4 h, l;
    split2(f[0], h.x, l.x); split2(f[1], h.y, l.y);
    split2(f[2], h.z, l.z); split2(f[3], h.w, l.w);
    *(ushort4*)(xh + i4) = h;
    *(ushort4*)(xl + i4) = l;
}

// ---- pack W^T concat (q|k|v) hi/lo ----
__global__ __launch_bounds__(256) void pack_w(
    const void* __restrict__ Wq, const void* __restrict__ Wk, const void* __restrict__ Wv,
    u16* __restrict__ WTh, u16* __restrict__ WTl, const int* __restrict__ flagp)
{
    const int k = blockIdx.x;
    const int n = blockIdx.y * 256 + threadIdx.x;
    const void* W = n < 512 ? Wq : n < 1024 ? Wk : Wv;
    const int nc = n & 511;
    float f = *flagp ? bf2f(((const u16*)W)[(size_t)k * 512 + nc])
                     : ((const float*)W)[(size_t)k * 512 + nc];
    u16 h, l; split2(f, h, l);
    WTh[(size_t)n * 512 + k] = h;
    WTl[(size_t)n * 512 + k] = l;
}

__global__ void pack_bias(
    const void* __restrict__ bq, const void* __restrict__ bk, const void* __restrict__ bv,
    float* __restrict__ bcat, const int* __restrict__ flagp)
{
    const int t = blockIdx.x * 256 + threadIdx.x;
    const void* b = t < 512 ? bq : t < 1024 ? bk : bv;
    const int i = t & 511;
    bcat[t] = *flagp ? bf2f(((const u16*)b)[i]) : ((const float*)b)[i];
}

// ---- fused 3-term split GEMM: C = Ah Bh^T + Al Bh^T + Ah Bl^T ----
// 128x128 tile, BK=32, 4 LDS arrays staged once per k0.
// EPI 0: fp32 C (scores). EPI 2: proj epilogue (split q/k, vT, +bias).
template <int EPI>
__global__ __launch_bounds__(256) void gemm_split3(
    const u16* __restrict__ Ah_, const u16* __restrict__ Al_,
    const u16* __restrict__ Bh_, const u16* __restrict__ Bl_,
    void* __restrict__ Cp, const float* __restrict__ biasf,
    u16* __restrict__ O1h, u16* __restrict__ O1l,
    u16* __restrict__ O2h, u16* __restrict__ O2l,
    u16* __restrict__ O3t,
    int K, int lda, int ldb, int ldc, long sA, long sB, long sC)
{
    const int tid = threadIdx.x;
    const int lane = tid & 63, wav = tid >> 6;
    const int l31 = lane & 31, lh = lane >> 5;
    const int m0 = blockIdx.y * 128, n0 = blockIdx.x * 128;
    const int bm = (wav >> 1) * 64, bn = (wav & 1) * 64;

    const u16* Ah = Ah_ + (size_t)blockIdx.z * sA;
    const u16* Al = Al_ + (size_t)blockIdx.z * sA;
    const u16* Bh = Bh_ + (size_t)blockIdx.z * sB;
    const u16* Bl = Bl_ + (size_t)blockIdx.z * sB;

    __shared__ __align__(16) u16 sAh[4096], sAl[4096];   // 128 x 32 each
    __shared__ __align__(16) u16 sBh[4096], sBl[4096];

    // staging: linear chunk i -> row r=i>>2, slot s=i&3 holds chunk c=s^((r>>2)&1)
    const int r0 = tid >> 2;
    const int c0 = ((tid & 3) ^ ((r0 >> 2) & 1)) * 8;
    const size_t aoff0 = (size_t)(m0 + r0) * lda + c0;
    const size_t aoff1 = aoff0 + (size_t)64 * lda;
    const size_t boff0 = (size_t)(n0 + r0) * ldb + c0;
    const size_t boff1 = boff0 + (size_t)64 * ldb;

    // frag read: row m, chunk c -> slot c ^ ((m>>2)&1); per-lane g
    const int g = (l31 >> 2) & 1;
    const int rowA0 = (bm + l31) * 32, rowA1 = (bm + 32 + l31) * 32;
    const int rowB0 = (bn + l31) * 32, rowB1 = (bn + 32 + l31) * 32;

    f32x16 acc[2][2];
#pragma unroll
    for (int i = 0; i < 2; i++)
#pragma unroll
        for (int j = 0; j < 2; j++)
#pragma unroll
            for (int r = 0; r < 16; r++) acc[i][j][r] = 0.f;

    for (int k0 = 0; k0 < K; k0 += 32) {
        gl16(Ah + aoff0 + k0, sAh + wav * 512);
        gl16(Ah + aoff1 + k0, sAh + 2048 + wav * 512);
        gl16(Al + aoff0 + k0, sAl + wav * 512);
        gl16(Al + aoff1 + k0, sAl + 2048 + wav * 512);
        gl16(Bh + boff0 + k0, sBh + wav * 512);
        gl16(Bh + boff1 + k0, sBh + 2048 + wav * 512);
        gl16(Bl + boff0 + k0, sBl + wav * 512);
        gl16(Bl + boff1 + k0, sBl + 2048 + wav * 512);
        __syncthreads();

#pragma unroll
        for (int h = 0; h < 2; h++) {
            const int so = ((h * 2 + lh) ^ g) * 8;
            bf16x8 ah[2], al[2], bh[2], bl[2];
            ah[0] = *(const bf16x8*)&sAh[rowA0 + so];
            ah[1] = *(const bf16x8*)&sAh[rowA1 + so];
            al[0] = *(const bf16x8*)&sAl[rowA0 + so];
            al[1] = *(const bf16x8*)&sAl[rowA1 + so];
            bh[0] = *(const bf16x8*)&sBh[rowB0 + so];
            bh[1] = *(const bf16x8*)&sBh[rowB1 + so];
            bl[0] = *(const bf16x8*)&sBl[rowB0 + so];
            bl[1] = *(const bf16x8*)&sBl[rowB1 + so];
#pragma unroll
            for (int i = 0; i < 2; i++)
#pragma unroll
                for (int j = 0; j < 2; j++) {
                    acc[i][j] = mfma32(ah[i], bh[j], acc[i][j]);
                    acc[i][j] = mfma32(al[i], bh[j], acc[i][j]);
                    acc[i][j] = mfma32(ah[i], bl[j], acc[i][j]);
                }
        }
        __syncthreads();
    }

    // ---- epilogue: 32x32 C/D layout col=lane&31, row=(r&3)+8*(r>>2)+4*lh ----
    if (EPI == 2) {
        const int mode = blockIdx.x >> 2;   // 0=q 1=k 2=v
#pragma unroll
        for (int it = 0; it < 2; it++)
#pragma unroll
            for (int jt = 0; jt < 2; jt++) {
                const int gcol = n0 + bn + jt * 32 + l31;
                const int lcol = gcol & 511;
                const float badd = biasf[gcol];
#pragma unroll
                for (int r = 0; r < 16; r++) {
                    const int row = m0 + bm + it * 32 + (r & 3) + 8 * (r >> 2) + 4 * lh;
                    const float v = acc[it][jt][r] + badd;
                    if (mode == 0) {
                        u16 hh, ll; split2(v, hh, ll);
                        O1h[(size_t)row * 512 + lcol] = hh;
                        O1l[(size_t)row * 512 + lcol] = ll;
                    } else if (mode == 1) {
                        u16 hh, ll; split2(v, hh, ll);
                        O2h[(size_t)row * 512 + lcol] = hh;
                        O2l[(size_t)row * 512 + lcol] = ll;
                    } else {
                        O3t[(size_t)lcol * 16384 + row] = f2bf(v);
                    }
                }
            }
    } else {
        float* Cf = (float*)Cp;
        const long coff = (long)blockIdx.z * sC;
#pragma unroll
        for (int it = 0; it < 2; it++)
#pragma unroll
            for (int jt = 0; jt < 2; jt++) {
                const int col = n0 + bn + jt * 32 + l31;
#pragma unroll
                for (int r = 0; r < 16; r++) {
                    const int row = m0 + bm + it * 32 + (r & 3) + 8 * (r >> 2) + 4 * lh;
                    Cf[(size_t)(coff + (long)row * ldc + col)] = acc[it][jt][r];
                }
            }
    }
}

// ---- 1-term PV GEMM: C = A B^T, BK=64, 32x32x16, flag-dtyped output ----
__global__ __launch_bounds__(256) void gemm_pv(
    const u16* __restrict__ A_, const u16* __restrict__ B_,
    void* __restrict__ Cp, const int* __restrict__ flagp,
    int K, int lda, int ldb, int ldc, long sA, long sB, long sC, long cbase)
{
    const int tid = threadIdx.x;
    const int lane = tid & 63, wav = tid >> 6;
    const int l31 = lane & 31, lh = lane >> 5;
    const int m0 = blockIdx.y * 128, n0 = blockIdx.x * 128;
    const int bm = (wav >> 1) * 64, bn = (wav & 1) * 64;

    const u16* A = A_ + (size_t)blockIdx.z * sA;
    const u16* B = B_ + (size_t)blockIdx.z * sB;

    __shared__ __align__(16) u16 As[8192], Bs[8192];   // 128 x 64 each

    // staging: i -> row r=i>>3, slot s=i&7 holds chunk c=s^(r&7)
    const int r0 = tid >> 3;
    const int c0 = ((tid & 7) ^ (r0 & 7)) * 8;
    size_t aoff[4], boff[4];
#pragma unroll
    for (int j = 0; j < 4; j++) {
        aoff[j] = (size_t)(m0 + r0 + j * 32) * lda + c0;
        boff[j] = (size_t)(n0 + r0 + j * 32) * ldb + c0;
    }
    const int g7 = l31 & 7;
    const int rowA0 = (bm + l31) * 64, rowA1 = (bm + 32 + l31) * 64;
    const int rowB0 = (bn + l31) * 64, rowB1 = (bn + 32 + l31) * 64;

    f32x16 acc[2][2];
#pragma unroll
    for (int i = 0; i < 2; i++)
#pragma unroll
        for (int j = 0; j < 2; j++)
#pragma unroll
            for (int r = 0; r < 16; r++) acc[i][j][r] = 0.f;

    for (int k0 = 0; k0 < K; k0 += 64) {
#pragma unroll
        for (int j = 0; j < 4; j++) {
            gl16(A + aoff[j] + k0, As + j * 2048 + wav * 512);
            gl16(B + boff[j] + k0, Bs + j * 2048 + wav * 512);
        }
        __syncthreads();

#pragma unroll
        for (int h = 0; h < 4; h++) {
            const int so = ((h * 2 + lh) ^ g7) * 8;
            bf16x8 af[2], bf[2];
            af[0] = *(const bf16x8*)&As[rowA0 + so];
            af[1] = *(const bf16x8*)&As[rowA1 + so];
            bf[0] = *(const bf16x8*)&Bs[rowB0 + so];
            bf[1] = *(const bf16x8*)&Bs[rowB1 + so];
#pragma unroll
            for (int i = 0; i < 2; i++)
#pragma unroll
                for (int j = 0; j < 2; j++)
                    acc[i][j] = mfma32(af[i], bf[j], acc[i][j]);
        }
        __syncthreads();
    }

    const int isbf = *flagp;
    float* Cf = (float*)Cp;
    u16* Cb = (u16*)Cp;
    const long coff = cbase + (long)blockIdx.z * sC;
#pragma unroll
    for (int it = 0; it < 2; it++)
#pragma unroll
        for (int jt = 0; jt < 2; jt++) {
            const int col = n0 + bn + jt * 32 + l31;
#pragma unroll
            for (int r = 0; r < 16; r++) {
                const int row = m0 + bm + it * 32 + (r & 3) + 8 * (r >> 2) + 4 * lh;
                const size_t idx = (size_t)(coff + (long)row * ldc + col);
                if (isbf) Cb[idx] = f2bf(acc[it][jt][r]);
                else Cf[idx] = acc[it][jt][r];
            }
        }
}

// ---- softmax: fp32 row -> bf16 P in place ----
__global__ __launch_bounds__(256) void softmax_k(float* __restrict__ sc)
{
    float* srow = sc + (size_t)blockIdx.x * S_LEN;
    const int tid = threadIdx.x;

    float4 a = ((const float4*)srow)[tid];
    float4 b = ((const float4*)srow)[256 + tid];

    float m = fmaxf(fmaxf(fmaxf(a.x, a.y), fmaxf(a.z, a.w)),
                    fmaxf(fmaxf(b.x, b.y), fmaxf(b.z, b.w)));
#pragma unroll
    for (int off = 32; off > 0; off >>= 1) m = fmaxf(m, __shfl_down(m, off));

    __shared__ float redm[4], reds[4];
    if ((tid & 63) == 0) redm[tid >> 6] = m;
    __syncthreads();
    m = fmaxf(fmaxf(redm[0], redm[1]), fmaxf(redm[2], redm[3]));

    a.x = __expf(a.x - m); a.y = __expf(a.y - m);
    a.z = __expf(a.z - m); a.w = __expf(a.w - m);
    b.x = __expf(b.x - m); b.y = __expf(b.y - m);
    b.z = __expf(b.z - m); b.w = __expf(b.w - m);
    float s = a.x + a.y + a.z + a.w + b.x + b.y + b.z + b.w;
#pragma unroll
    for (int off = 32; off > 0; off >>= 1) s += __shfl_down(s, off);
    if ((tid & 63) == 0) reds[tid >> 6] = s;
    __syncthreads();
    s = reds[0] + reds[1] + reds[2] + reds[3];

    const float inv = 1.0f / s;
    ushort4 pa, pb;
    pa.x = f2bf(a.x * inv); pa.y = f2bf(a.y * inv);
    pa.z = f2bf(a.z * inv); pa.w = f2bf(a.w * inv);
    pb.x = f2bf(b.x * inv); pb.y = f2bf(b.y * inv);
    pb.z = f2bf(b.z * inv); pb.w = f2bf(b.w * inv);
    ((ushort4*)srow)[tid] = pa;
    ((ushort4*)srow)[256 + tid] = pb;
}

extern "C" void kernel_launch(void* const* d_in, const int* in_sizes, int n_in,
                              void* d_out, int out_size, void* d_ws, size_t ws_size,
                              hipStream_t stream)
{
    const void* x  = d_in[0];
    const void* Wq = d_in[1]; const void* bq = d_in[2];
    const void* Wk = d_in[3]; const void* bk = d_in[4];
    const void* Wv = d_in[5]; const void* bv = d_in[6];

    const int S = S_LEN, D = D_DIM;
    const long SD = (long)S * D;

    char* w = (char*)d_ws;
    int*   flag = (int*)w;
    u16*   WTh  = (u16*)(w + 256);
    u16*   WTl  = WTh + 786432;
    float* bcat = (float*)(WTl + 786432);
    u16*   qh   = (u16*)(w + 3152128);
    u16*   ql   = qh + 8388608;
    u16*   kh   = ql + 8388608;
    u16*   kl   = kh + 8388608;
    u16*   vT   = kl + 8388608;                 // [512][16384]
    u16*   xh   = vT + 8388608;
    u16*   xl   = xh + 8388608;
    float* scA  = (float*)xh;                   // scores arena reuses x-split region

    const size_t avail = ws_size > 87038208ull ? ws_size - 87038208ull : 0;
    const size_t perb = (size_t)S * S * 4;
    const int c = avail >= 8 * perb ? 8 : avail >= 4 * perb ? 4 : avail >= 2 * perb ? 2 : 1;

    dim3 blk(256);

    detect_k<<<1, 64, 0, stream>>>((const u16*)x, flag);
    split_x<<<8192, blk, 0, stream>>>(x, xh, xl, flag);
    pack_w<<<dim3(512, 6), blk, 0, stream>>>(Wq, Wk, Wv, WTh, WTl, flag);
    pack_bias<<<6, blk, 0, stream>>>(bq, bk, bv, bcat, flag);

    // fused q|k|v projection: [16384,512] x [512,1536]^T(packed), 3-term split
    gemm_split3<2><<<dim3(12, 128, 1), blk, 0, stream>>>(
        xh, xl, WTh, WTl, nullptr, bcat,
        qh, ql, kh, kl, vT, 512, 512, 512, 0, 0, 0, 0);

    for (int cb = 0; cb < B_N; cb += c) {
        const size_t off = (size_t)cb * SD;
        // scores = qh kh^T + ql kh^T + qh kl^T  (fp32)
        gemm_split3<0><<<dim3(16, 16, c), blk, 0, stream>>>(
            qh + off, ql + off, kh + off, kl + off,
            scA, nullptr, nullptr, nullptr, nullptr, nullptr, nullptr,
            512, 512, 512, S, SD, SD, (long)S * S);
        softmax_k<<<c * S, blk, 0, stream>>>(scA);
        // out = P @ v via vT rows
        gemm_pv<<<dim3(4, 16, c), blk, 0, stream>>>(
            (const u16*)scA, vT + (size_t)cb * S, d_out, flag,
            S, 2 * S, B_N * S, D, 2ll * S * S, S, SD, (long)cb * SD);
    }
}

// Round 5
// 411.141 us; speedup vs baseline: 2.4304x; 1.0198x over previous
//
#include <hip/hip_runtime.h>

// Self-attention B=8 S=2048 D=512, fp32-vs-bf16 input auto-detect.
// R5: fix split3 LDS swizzle to full 4-slot XOR (R4's 2-slot XOR caused
// 4-way bank conflicts, 6.3e6/dispatch). Numerics identical to R2-R4.

typedef unsigned short u16;
typedef unsigned int u32;
typedef __attribute__((ext_vector_type(8))) __bf16 bf16x8;
typedef __attribute__((ext_vector_type(16))) float f32x16;

#define S_LEN 2048
#define D_DIM 512
#define B_N 8

__device__ __forceinline__ u16 f2bf(float f) {
    u32 u = __float_as_uint(f);
    u32 r = u + 0x7FFFu + ((u >> 16) & 1u);   // RNE
    return (u16)(r >> 16);
}
__device__ __forceinline__ float bf2f(u16 h) {
    return __uint_as_float((u32)h << 16);
}
__device__ __forceinline__ void split2(float f, u16& h, u16& l) {
    h = f2bf(f);
    l = f2bf(f - bf2f(h));
}
__device__ __forceinline__ void gl16(const u16* g, u16* l) {
    __builtin_amdgcn_global_load_lds(
        (const __attribute__((address_space(1))) void*)g,
        (__attribute__((address_space(3))) void*)l, 16, 0, 0);
}
__device__ __forceinline__ f32x16 mfma32(bf16x8 a, bf16x8 b, f32x16 c) {
    return __builtin_amdgcn_mfma_f32_32x32x16_bf16(a, b, c, 0, 0, 0);
}

// ---- dtype detector ----
__global__ void detect_k(const u16* __restrict__ x, int* __restrict__ flag)
{
    int t = threadIdx.x;
    u16 u = x[2 * t];
    int e = (u >> 7) & 0xFF;
    int sane = (e == 0) || (e >= 110 && e <= 140);
    unsigned long long b = __ballot(sane);
    if (t == 0) *flag = (__popcll(b) >= 32) ? 1 : 0;
}

// ---- split x into hi/lo bf16 ----
__global__ __launch_bounds__(256) void split_x(
    const void* __restrict__ X, u16* __restrict__ xh, u16* __restrict__ xl,
    const int* __restrict__ flagp)
{
    const size_t i4 = ((size_t)blockIdx.x * 256 + threadIdx.x) * 4;
    float f[4];
    if (*flagp) {
        ushort4 u = *(const ushort4*)((const u16*)X + i4);
        f[0] = bf2f(u.x); f[1] = bf2f(u.y); f[2] = bf2f(u.z); f[3] = bf2f(u.w);
    } else {
        float4 ff = *(const float4*)((const float*)X + i4);
        f[0] = ff.x; f[1] = ff.y; f[2] = ff.z; f[3] = ff.w;
    }
    ushort4 h, l;
    split2(f[0], h.x, l.x); split2(f[1], h.y, l.y);
    split2(f[2], h.z, l.z); split2(f[3], h.w, l.w);
    *(ushort4*)(xh + i4) = h;
    *(ushort4*)(xl + i4) = l;
}

// ---- pack W^T concat (q|k|v) hi/lo ----
__global__ __launch_bounds__(256) void pack_w(
    const void* __restrict__ Wq, const void* __restrict__ Wk, const void* __restrict__ Wv,
    u16* __restrict__ WTh, u16* __restrict__ WTl, const int* __restrict__ flagp)
{
    const int k = blockIdx.x;
    const int n = blockIdx.y * 256 + threadIdx.x;
    const void* W = n < 512 ? Wq : n < 1024 ? Wk : Wv;
    const int nc = n & 511;
    float f = *flagp ? bf2f(((const u16*)W)[(size_t)k * 512 + nc])
                     : ((const float*)W)[(size_t)k * 512 + nc];
    u16 h, l; split2(f, h, l);
    WTh[(size_t)n * 512 + k] = h;
    WTl[(size_t)n * 512 + k] = l;
}

__global__ void pack_bias(
    const void* __restrict__ bq, const void* __restrict__ bk, const void* __restrict__ bv,
    float* __restrict__ bcat, const int* __restrict__ flagp)
{
    const int t = blockIdx.x * 256 + threadIdx.x;
    const void* b = t < 512 ? bq : t < 1024 ? bk : bv;
    const int i = t & 511;
    bcat[t] = *flagp ? bf2f(((const u16*)b)[i]) : ((const float*)b)[i];
}

// ---- fused 3-term split GEMM: C = Ah Bh^T + Al Bh^T + Ah Bl^T ----
// 128x128 tile, BK=32, 4 LDS arrays staged once per k0.
// Swizzle: global chunk c lives in LDS slot c ^ ((row>>1)&3)  (4-slot XOR,
// 2 lanes per 4-bank group within every 16-lane quarter -> conflict-free).
template <int EPI>
__global__ __launch_bounds__(256) void gemm_split3(
    const u16* __restrict__ Ah_, const u16* __restrict__ Al_,
    const u16* __restrict__ Bh_, const u16* __restrict__ Bl_,
    void* __restrict__ Cp, const float* __restrict__ biasf,
    u16* __restrict__ O1h, u16* __restrict__ O1l,
    u16* __restrict__ O2h, u16* __restrict__ O2l,
    u16* __restrict__ O3t,
    int K, int lda, int ldb, int ldc, long sA, long sB, long sC)
{
    const int tid = threadIdx.x;
    const int lane = tid & 63, wav = tid >> 6;
    const int l31 = lane & 31, lh = lane >> 5;
    const int m0 = blockIdx.y * 128, n0 = blockIdx.x * 128;
    const int bm = (wav >> 1) * 64, bn = (wav & 1) * 64;

    const u16* Ah = Ah_ + (size_t)blockIdx.z * sA;
    const u16* Al = Al_ + (size_t)blockIdx.z * sA;
    const u16* Bh = Bh_ + (size_t)blockIdx.z * sB;
    const u16* Bl = Bl_ + (size_t)blockIdx.z * sB;

    __shared__ __align__(16) u16 sAh[4096], sAl[4096];   // 128 x 32 each
    __shared__ __align__(16) u16 sBh[4096], sBl[4096];

    // staging: linear chunk i -> row r=i>>2, slot s=i&3 holds chunk c=s^((r>>1)&3)
    const int r0 = tid >> 2;
    const int c0 = ((tid & 3) ^ ((r0 >> 1) & 3)) * 8;
    const size_t aoff0 = (size_t)(m0 + r0) * lda + c0;
    const size_t aoff1 = aoff0 + (size_t)64 * lda;
    const size_t boff0 = (size_t)(n0 + r0) * ldb + c0;
    const size_t boff1 = boff0 + (size_t)64 * ldb;

    // frag read: global chunk (2h+lh) of row m sits in slot (2h+lh)^((m>>1)&3)
    const int g = (l31 >> 1) & 3;
    const int rowA0 = (bm + l31) * 32, rowA1 = (bm + 32 + l31) * 32;
    const int rowB0 = (bn + l31) * 32, rowB1 = (bn + 32 + l31) * 32;

    f32x16 acc[2][2];
#pragma unroll
    for (int i = 0; i < 2; i++)
#pragma unroll
        for (int j = 0; j < 2; j++)
#pragma unroll
            for (int r = 0; r < 16; r++) acc[i][j][r] = 0.f;

    for (int k0 = 0; k0 < K; k0 += 32) {
        gl16(Ah + aoff0 + k0, sAh + wav * 512);
        gl16(Ah + aoff1 + k0, sAh + 2048 + wav * 512);
        gl16(Al + aoff0 + k0, sAl + wav * 512);
        gl16(Al + aoff1 + k0, sAl + 2048 + wav * 512);
        gl16(Bh + boff0 + k0, sBh + wav * 512);
        gl16(Bh + boff1 + k0, sBh + 2048 + wav * 512);
        gl16(Bl + boff0 + k0, sBl + wav * 512);
        gl16(Bl + boff1 + k0, sBl + 2048 + wav * 512);
        __syncthreads();

#pragma unroll
        for (int h = 0; h < 2; h++) {
            const int so = ((h * 2 + lh) ^ g) * 8;
            bf16x8 ah[2], al[2], bh[2], bl[2];
            ah[0] = *(const bf16x8*)&sAh[rowA0 + so];
            ah[1] = *(const bf16x8*)&sAh[rowA1 + so];
            al[0] = *(const bf16x8*)&sAl[rowA0 + so];
            al[1] = *(const bf16x8*)&sAl[rowA1 + so];
            bh[0] = *(const bf16x8*)&sBh[rowB0 + so];
            bh[1] = *(const bf16x8*)&sBh[rowB1 + so];
            bl[0] = *(const bf16x8*)&sBl[rowB0 + so];
            bl[1] = *(const bf16x8*)&sBl[rowB1 + so];
#pragma unroll
            for (int i = 0; i < 2; i++)
#pragma unroll
                for (int j = 0; j < 2; j++) {
                    acc[i][j] = mfma32(ah[i], bh[j], acc[i][j]);
                    acc[i][j] = mfma32(al[i], bh[j], acc[i][j]);
                    acc[i][j] = mfma32(ah[i], bl[j], acc[i][j]);
                }
        }
        __syncthreads();
    }

    // ---- epilogue: 32x32 C/D layout col=lane&31, row=(r&3)+8*(r>>2)+4*lh ----
    if (EPI == 2) {
        const int mode = blockIdx.x >> 2;   // 0=q 1=k 2=v
#pragma unroll
        for (int it = 0; it < 2; it++)
#pragma unroll
            for (int jt = 0; jt < 2; jt++) {
                const int gcol = n0 + bn + jt * 32 + l31;
                const int lcol = gcol & 511;
                const float badd = biasf[gcol];
#pragma unroll
                for (int r = 0; r < 16; r++) {
                    const int row = m0 + bm + it * 32 + (r & 3) + 8 * (r >> 2) + 4 * lh;
                    const float v = acc[it][jt][r] + badd;
                    if (mode == 0) {
                        u16 hh, ll; split2(v, hh, ll);
                        O1h[(size_t)row * 512 + lcol] = hh;
                        O1l[(size_t)row * 512 + lcol] = ll;
                    } else if (mode == 1) {
                        u16 hh, ll; split2(v, hh, ll);
                        O2h[(size_t)row * 512 + lcol] = hh;
                        O2l[(size_t)row * 512 + lcol] = ll;
                    } else {
                        O3t[(size_t)lcol * 16384 + row] = f2bf(v);
                    }
                }
            }
    } else {
        float* Cf = (float*)Cp;
        const long coff = (long)blockIdx.z * sC;
#pragma unroll
        for (int it = 0; it < 2; it++)
#pragma unroll
            for (int jt = 0; jt < 2; jt++) {
                const int col = n0 + bn + jt * 32 + l31;
#pragma unroll
                for (int r = 0; r < 16; r++) {
                    const int row = m0 + bm + it * 32 + (r & 3) + 8 * (r >> 2) + 4 * lh;
                    Cf[(size_t)(coff + (long)row * ldc + col)] = acc[it][jt][r];
                }
            }
    }
}

// ---- 1-term PV GEMM: C = A B^T, BK=64, 32x32x16, flag-dtyped output ----
__global__ __launch_bounds__(256) void gemm_pv(
    const u16* __restrict__ A_, const u16* __restrict__ B_,
    void* __restrict__ Cp, const int* __restrict__ flagp,
    int K, int lda, int ldb, int ldc, long sA, long sB, long sC, long cbase)
{
    const int tid = threadIdx.x;
    const int lane = tid & 63, wav = tid >> 6;
    const int l31 = lane & 31, lh = lane >> 5;
    const int m0 = blockIdx.y * 128, n0 = blockIdx.x * 128;
    const int bm = (wav >> 1) * 64, bn = (wav & 1) * 64;

    const u16* A = A_ + (size_t)blockIdx.z * sA;
    const u16* B = B_ + (size_t)blockIdx.z * sB;

    __shared__ __align__(16) u16 As[8192], Bs[8192];   // 128 x 64 each

    // staging: i -> row r=i>>3, slot s=i&7 holds chunk c=s^(r&7)
    const int r0 = tid >> 3;
    const int c0 = ((tid & 7) ^ (r0 & 7)) * 8;
    size_t aoff[4], boff[4];
#pragma unroll
    for (int j = 0; j < 4; j++) {
        aoff[j] = (size_t)(m0 + r0 + j * 32) * lda + c0;
        boff[j] = (size_t)(n0 + r0 + j * 32) * ldb + c0;
    }
    const int g7 = l31 & 7;
    const int rowA0 = (bm + l31) * 64, rowA1 = (bm + 32 + l31) * 64;
    const int rowB0 = (bn + l31) * 64, rowB1 = (bn + 32 + l31) * 64;

    f32x16 acc[2][2];
#pragma unroll
    for (int i = 0; i < 2; i++)
#pragma unroll
        for (int j = 0; j < 2; j++)
#pragma unroll
            for (int r = 0; r < 16; r++) acc[i][j][r] = 0.f;

    for (int k0 = 0; k0 < K; k0 += 64) {
#pragma unroll
        for (int j = 0; j < 4; j++) {
            gl16(A + aoff[j] + k0, As + j * 2048 + wav * 512);
            gl16(B + boff[j] + k0, Bs + j * 2048 + wav * 512);
        }
        __syncthreads();

#pragma unroll
        for (int h = 0; h < 4; h++) {
            const int so = ((h * 2 + lh) ^ g7) * 8;
            bf16x8 af[2], bf[2];
            af[0] = *(const bf16x8*)&As[rowA0 + so];
            af[1] = *(const bf16x8*)&As[rowA1 + so];
            bf[0] = *(const bf16x8*)&Bs[rowB0 + so];
            bf[1] = *(const bf16x8*)&Bs[rowB1 + so];
#pragma unroll
            for (int i = 0; i < 2; i++)
#pragma unroll
                for (int j = 0; j < 2; j++)
                    acc[i][j] = mfma32(af[i], bf[j], acc[i][j]);
        }
        __syncthreads();
    }

    const int isbf = *flagp;
    float* Cf = (float*)Cp;
    u16* Cb = (u16*)Cp;
    const long coff = cbase + (long)blockIdx.z * sC;
#pragma unroll
    for (int it = 0; it < 2; it++)
#pragma unroll
        for (int jt = 0; jt < 2; jt++) {
            const int col = n0 + bn + jt * 32 + l31;
#pragma unroll
            for (int r = 0; r < 16; r++) {
                const int row = m0 + bm + it * 32 + (r & 3) + 8 * (r >> 2) + 4 * lh;
                const size_t idx = (size_t)(coff + (long)row * ldc + col);
                if (isbf) Cb[idx] = f2bf(acc[it][jt][r]);
                else Cf[idx] = acc[it][jt][r];
            }
        }
}

// ---- softmax: fp32 row -> bf16 P in place ----
__global__ __launch_bounds__(256) void softmax_k(float* __restrict__ sc)
{
    float* srow = sc + (size_t)blockIdx.x * S_LEN;
    const int tid = threadIdx.x;

    float4 a = ((const float4*)srow)[tid];
    float4 b = ((const float4*)srow)[256 + tid];

    float m = fmaxf(fmaxf(fmaxf(a.x, a.y), fmaxf(a.z, a.w)),
                    fmaxf(fmaxf(b.x, b.y), fmaxf(b.z, b.w)));
#pragma unroll
    for (int off = 32; off > 0; off >>= 1) m = fmaxf(m, __shfl_down(m, off));

    __shared__ float redm[4], reds[4];
    if ((tid & 63) == 0) redm[tid >> 6] = m;
    __syncthreads();
    m = fmaxf(fmaxf(redm[0], redm[1]), fmaxf(redm[2], redm[3]));

    a.x = __expf(a.x - m); a.y = __expf(a.y - m);
    a.z = __expf(a.z - m); a.w = __expf(a.w - m);
    b.x = __expf(b.x - m); b.y = __expf(b.y - m);
    b.z = __expf(b.z - m); b.w = __expf(b.w - m);
    float s = a.x + a.y + a.z + a.w + b.x + b.y + b.z + b.w;
#pragma unroll
    for (int off = 32; off > 0; off >>= 1) s += __shfl_down(s, off);
    if ((tid & 63) == 0) reds[tid >> 6] = s;
    __syncthreads();
    s = reds[0] + reds[1] + reds[2] + reds[3];

    const float inv = 1.0f / s;
    ushort4 pa, pb;
    pa.x = f2bf(a.x * inv); pa.y = f2bf(a.y * inv);
    pa.z = f2bf(a.z * inv); pa.w = f2bf(a.w * inv);
    pb.x = f2bf(b.x * inv); pb.y = f2bf(b.y * inv);
    pb.z = f2bf(b.z * inv); pb.w = f2bf(b.w * inv);
    ((ushort4*)srow)[tid] = pa;
    ((ushort4*)srow)[256 + tid] = pb;
}

extern "C" void kernel_launch(void* const* d_in, const int* in_sizes, int n_in,
                              void* d_out, int out_size, void* d_ws, size_t ws_size,
                              hipStream_t stream)
{
    const void* x  = d_in[0];
    const void* Wq = d_in[1]; const void* bq = d_in[2];
    const void* Wk = d_in[3]; const void* bk = d_in[4];
    const void* Wv = d_in[5]; const void* bv = d_in[6];

    const int S = S_LEN, D = D_DIM;
    const long SD = (long)S * D;

    char* w = (char*)d_ws;
    int*   flag = (int*)w;
    u16*   WTh  = (u16*)(w + 256);
    u16*   WTl  = WTh + 786432;
    float* bcat = (float*)(WTl + 786432);
    u16*   qh   = (u16*)(w + 3152128);
    u16*   ql   = qh + 8388608;
    u16*   kh   = ql + 8388608;
    u16*   kl   = kh + 8388608;
    u16*   vT   = kl + 8388608;                 // [512][16384]
    u16*   xh   = vT + 8388608;
    u16*   xl   = xh + 8388608;
    float* scA  = (float*)xh;                   // scores arena reuses x-split region

    const size_t avail = ws_size > 87038208ull ? ws_size - 87038208ull : 0;
    const size_t perb = (size_t)S * S * 4;
    const int c = avail >= 8 * perb ? 8 : avail >= 4 * perb ? 4 : avail >= 2 * perb ? 2 : 1;

    dim3 blk(256);

    detect_k<<<1, 64, 0, stream>>>((const u16*)x, flag);
    split_x<<<8192, blk, 0, stream>>>(x, xh, xl, flag);
    pack_w<<<dim3(512, 6), blk, 0, stream>>>(Wq, Wk, Wv, WTh, WTl, flag);
    pack_bias<<<6, blk, 0, stream>>>(bq, bk, bv, bcat, flag);

    // fused q|k|v projection: [16384,512] x [512,1536]^T(packed), 3-term split
    gemm_split3<2><<<dim3(12, 128, 1), blk, 0, stream>>>(
        xh, xl, WTh, WTl, nullptr, bcat,
        qh, ql, kh, kl, vT, 512, 512, 512, 0, 0, 0, 0);

    for (int cb = 0; cb < B_N; cb += c) {
        const size_t off = (size_t)cb * SD;
        // scores = qh kh^T + ql kh^T + qh kl^T  (fp32)
        gemm_split3<0><<<dim3(16, 16, c), blk, 0, stream>>>(
            qh + off, ql + off, kh + off, kl + off,
            scA, nullptr, nullptr, nullptr, nullptr, nullptr, nullptr,
            512, 512, 512, S, SD, SD, (long)S * S);
        softmax_k<<<c * S, blk, 0, stream>>>(scA);
        // out = P @ v via vT rows
        gemm_pv<<<dim3(4, 16, c), blk, 0, stream>>>(
            (const u16*)scA, vT + (size_t)cb * S, d_out, flag,
            S, 2 * S, B_N * S, D, 2ll * S * S, S, SD, (long)cb * SD);
    }
}

// Round 8
// 293.091 us; speedup vs baseline: 3.4094x; 1.4028x over previous
//
#include <hip/hip_runtime.h>
#include <hip/hip_fp16.h>

// Self-attention B=8 S=2048 D=512, fp32-vs-bf16 input auto-detect.
// R8 = R6 resubmit with defensive fp16 header include (rounds 6/7 died in
// container infra before verification; source re-audited clean vs R5).
// Single-term fp16 GEMMs everywhere (3x less MFMA work than 3-term bf16
// split). m97-style K-loop, BK=64, global_load_lds, XOR(l&7) LDS swizzle.

typedef unsigned short u16;
typedef unsigned int u32;
typedef __attribute__((ext_vector_type(8))) _Float16 f16x8;
typedef __attribute__((ext_vector_type(16))) float f32x16;

#define S_LEN 2048
#define D_DIM 512
#define B_N 8

__device__ __forceinline__ u16 f2bf(float f) {
    u32 u = __float_as_uint(f);
    u32 r = u + 0x7FFFu + ((u >> 16) & 1u);   // RNE
    return (u16)(r >> 16);
}
__device__ __forceinline__ float bf2f(u16 h) {
    return __uint_as_float((u32)h << 16);
}
__device__ __forceinline__ u16 f2h(float f) {
    _Float16 h = (_Float16)f;                 // RNE
    return *(u16*)&h;
}
__device__ __forceinline__ void gl16(const u16* g, u16* l) {
    __builtin_amdgcn_global_load_lds(
        (const __attribute__((address_space(1))) void*)g,
        (__attribute__((address_space(3))) void*)l, 16, 0, 0);
}
__device__ __forceinline__ f32x16 mfma16(f16x8 a, f16x8 b, f32x16 c) {
    return __builtin_amdgcn_mfma_f32_32x32x16_f16(a, b, c, 0, 0, 0);
}

// ---- dtype detector ----
__global__ void detect_k(const u16* __restrict__ x, int* __restrict__ flag)
{
    int t = threadIdx.x;
    u16 u = x[2 * t];
    int e = (u >> 7) & 0xFF;
    int sane = (e == 0) || (e >= 110 && e <= 140);
    unsigned long long b = __ballot(sane);
    if (t == 0) *flag = (__popcll(b) >= 32) ? 1 : 0;
}

// ---- convert x to fp16 ----
__global__ __launch_bounds__(256) void cvt_x(
    const void* __restrict__ X, u16* __restrict__ xf,
    const int* __restrict__ flagp)
{
    const size_t i4 = ((size_t)blockIdx.x * 256 + threadIdx.x) * 4;
    float f[4];
    if (*flagp) {
        ushort4 u = *(const ushort4*)((const u16*)X + i4);
        f[0] = bf2f(u.x); f[1] = bf2f(u.y); f[2] = bf2f(u.z); f[3] = bf2f(u.w);
    } else {
        float4 ff = *(const float4*)((const float*)X + i4);
        f[0] = ff.x; f[1] = ff.y; f[2] = ff.z; f[3] = ff.w;
    }
    ushort4 h;
    h.x = f2h(f[0]); h.y = f2h(f[1]); h.z = f2h(f[2]); h.w = f2h(f[3]);
    *(ushort4*)(xf + i4) = h;
}

// ---- pack W^T concat (q|k|v) fp16: WT[n 0..1535][k 0..511] ----
__global__ __launch_bounds__(256) void pack_w(
    const void* __restrict__ Wq, const void* __restrict__ Wk, const void* __restrict__ Wv,
    u16* __restrict__ WT, const int* __restrict__ flagp)
{
    const int k = blockIdx.x;
    const int n = blockIdx.y * 256 + threadIdx.x;
    const void* W = n < 512 ? Wq : n < 1024 ? Wk : Wv;
    const int nc = n & 511;
    float f = *flagp ? bf2f(((const u16*)W)[(size_t)k * 512 + nc])
                     : ((const float*)W)[(size_t)k * 512 + nc];
    WT[(size_t)n * 512 + k] = f2h(f);
}

__global__ void pack_bias(
    const void* __restrict__ bq, const void* __restrict__ bk, const void* __restrict__ bv,
    float* __restrict__ bcat, const int* __restrict__ flagp)
{
    const int t = blockIdx.x * 256 + threadIdx.x;
    const void* b = t < 512 ? bq : t < 1024 ? bk : bv;
    const int i = t & 511;
    bcat[t] = *flagp ? bf2f(((const u16*)b)[i]) : ((const float*)b)[i];
}

// ---- unified fp16 BT-GEMM: C[M,N] = A[M,K] * B[N,K]^T ----
// 128x128 tile, BK=64. Staging: slot s of row r holds global chunk s^(r&7).
// EPI 0: fp32 C (scores). EPI 1: flag-dtyped C (out). EPI 2: proj q|k|vT +bias.
template <int EPI>
__global__ __launch_bounds__(256) void gemm_f16(
    const u16* __restrict__ A_, const u16* __restrict__ B_,
    void* __restrict__ Cp, const float* __restrict__ biasf,
    u16* __restrict__ Oq, u16* __restrict__ Ok, u16* __restrict__ OvT,
    const int* __restrict__ flagp,
    int K, int lda, int ldb, int ldc, long sA, long sB, long sC, long cbase)
{
    const int tid = threadIdx.x;
    const int lane = tid & 63, wav = tid >> 6;
    const int l31 = lane & 31, lh = lane >> 5;
    const int m0 = blockIdx.y * 128, n0 = blockIdx.x * 128;
    const int bm = (wav >> 1) * 64, bn = (wav & 1) * 64;

    const u16* A = A_ + (size_t)blockIdx.z * sA;
    const u16* B = B_ + (size_t)blockIdx.z * sB;

    __shared__ __align__(16) u16 As[8192], Bs[8192];   // 128 x 64 fp16 each

    const int r0 = tid >> 3;
    const int c0 = ((tid & 7) ^ (r0 & 7)) * 8;
    size_t aoff[4], boff[4];
#pragma unroll
    for (int j = 0; j < 4; j++) {
        aoff[j] = (size_t)(m0 + r0 + j * 32) * lda + c0;
        boff[j] = (size_t)(n0 + r0 + j * 32) * ldb + c0;
    }
    const int g7 = l31 & 7;
    const int rowA0 = (bm + l31) * 64, rowA1 = (bm + 32 + l31) * 64;
    const int rowB0 = (bn + l31) * 64, rowB1 = (bn + 32 + l31) * 64;

    f32x16 acc[2][2];
#pragma unroll
    for (int i = 0; i < 2; i++)
#pragma unroll
        for (int j = 0; j < 2; j++)
#pragma unroll
            for (int r = 0; r < 16; r++) acc[i][j][r] = 0.f;

    for (int k0 = 0; k0 < K; k0 += 64) {
#pragma unroll
        for (int j = 0; j < 4; j++) {
            gl16(A + aoff[j] + k0, As + j * 2048 + wav * 512);
            gl16(B + boff[j] + k0, Bs + j * 2048 + wav * 512);
        }
        __syncthreads();

#pragma unroll
        for (int h = 0; h < 4; h++) {
            const int so = ((h * 2 + lh) ^ g7) * 8;
            f16x8 af[2], bfr[2];
            af[0] = *(const f16x8*)&As[rowA0 + so];
            af[1] = *(const f16x8*)&As[rowA1 + so];
            bfr[0] = *(const f16x8*)&Bs[rowB0 + so];
            bfr[1] = *(const f16x8*)&Bs[rowB1 + so];
#pragma unroll
            for (int i = 0; i < 2; i++)
#pragma unroll
                for (int j = 0; j < 2; j++)
                    acc[i][j] = mfma16(af[i], bfr[j], acc[i][j]);
        }
        __syncthreads();
    }

    // ---- epilogue: 32x32 C/D layout col=lane&31, row=(r&3)+8*(r>>2)+4*lh ----
    if (EPI == 2) {
        const int mode = blockIdx.x >> 2;   // 0=q 1=k 2=v
#pragma unroll
        for (int it = 0; it < 2; it++)
#pragma unroll
            for (int jt = 0; jt < 2; jt++) {
                const int gcol = n0 + bn + jt * 32 + l31;
                const int lcol = gcol & 511;
                const float badd = biasf[gcol];
#pragma unroll
                for (int r = 0; r < 16; r++) {
                    const int row = m0 + bm + it * 32 + (r & 3) + 8 * (r >> 2) + 4 * lh;
                    const float v = acc[it][jt][r] + badd;
                    if (mode == 0)      Oq [(size_t)row * 512 + lcol] = f2h(v);
                    else if (mode == 1) Ok [(size_t)row * 512 + lcol] = f2h(v);
                    else                OvT[(size_t)lcol * 16384 + row] = f2h(v);
                }
            }
    } else if (EPI == 0) {
        float* Cf = (float*)Cp;
        const long coff = (long)blockIdx.z * sC;
#pragma unroll
        for (int it = 0; it < 2; it++)
#pragma unroll
            for (int jt = 0; jt < 2; jt++) {
                const int col = n0 + bn + jt * 32 + l31;
#pragma unroll
                for (int r = 0; r < 16; r++) {
                    const int row = m0 + bm + it * 32 + (r & 3) + 8 * (r >> 2) + 4 * lh;
                    Cf[(size_t)(coff + (long)row * ldc + col)] = acc[it][jt][r];
                }
            }
    } else {
        const int isbf = *flagp;
        float* Cf = (float*)Cp;
        u16* Cb = (u16*)Cp;
        const long coff = cbase + (long)blockIdx.z * sC;
#pragma unroll
        for (int it = 0; it < 2; it++)
#pragma unroll
            for (int jt = 0; jt < 2; jt++) {
                const int col = n0 + bn + jt * 32 + l31;
#pragma unroll
                for (int r = 0; r < 16; r++) {
                    const int row = m0 + bm + it * 32 + (r & 3) + 8 * (r >> 2) + 4 * lh;
                    const size_t idx = (size_t)(coff + (long)row * ldc + col);
                    if (isbf) Cb[idx] = f2bf(acc[it][jt][r]);
                    else Cf[idx] = acc[it][jt][r];
                }
            }
    }
}

// ---- softmax: fp32 row -> fp16 P in place (first half of row bytes) ----
__global__ __launch_bounds__(256) void softmax_k(float* __restrict__ sc)
{
    float* srow = sc + (size_t)blockIdx.x * S_LEN;
    const int tid = threadIdx.x;

    float4 a = ((const float4*)srow)[tid];
    float4 b = ((const float4*)srow)[256 + tid];

    float m = fmaxf(fmaxf(fmaxf(a.x, a.y), fmaxf(a.z, a.w)),
                    fmaxf(fmaxf(b.x, b.y), fmaxf(b.z, b.w)));
#pragma unroll
    for (int off = 32; off > 0; off >>= 1) m = fmaxf(m, __shfl_down(m, off));

    __shared__ float redm[4], reds[4];
    if ((tid & 63) == 0) redm[tid >> 6] = m;
    __syncthreads();
    m = fmaxf(fmaxf(redm[0], redm[1]), fmaxf(redm[2], redm[3]));

    a.x = __expf(a.x - m); a.y = __expf(a.y - m);
    a.z = __expf(a.z - m); a.w = __expf(a.w - m);
    b.x = __expf(b.x - m); b.y = __expf(b.y - m);
    b.z = __expf(b.z - m); b.w = __expf(b.w - m);
    float s = a.x + a.y + a.z + a.w + b.x + b.y + b.z + b.w;
#pragma unroll
    for (int off = 32; off > 0; off >>= 1) s += __shfl_down(s, off);
    if ((tid & 63) == 0) reds[tid >> 6] = s;
    __syncthreads();
    s = reds[0] + reds[1] + reds[2] + reds[3];

    const float inv = 1.0f / s;
    ushort4 pa, pb;
    pa.x = f2h(a.x * inv); pa.y = f2h(a.y * inv);
    pa.z = f2h(a.z * inv); pa.w = f2h(a.w * inv);
    pb.x = f2h(b.x * inv); pb.y = f2h(b.y * inv);
    pb.z = f2h(b.z * inv); pb.w = f2h(b.w * inv);
    ((ushort4*)srow)[tid] = pa;
    ((ushort4*)srow)[256 + tid] = pb;
}

extern "C" void kernel_launch(void* const* d_in, const int* in_sizes, int n_in,
                              void* d_out, int out_size, void* d_ws, size_t ws_size,
                              hipStream_t stream)
{
    const void* x  = d_in[0];
    const void* Wq = d_in[1]; const void* bq = d_in[2];
    const void* Wk = d_in[3]; const void* bk = d_in[4];
    const void* Wv = d_in[5]; const void* bv = d_in[6];

    const int S = S_LEN, D = D_DIM;
    const long SD = (long)S * D;                      // 1,048,576

    char* w = (char*)d_ws;
    int*   flag = (int*)w;                            // @0
    u16*   WT   = (u16*)(w + 1024);                   // 1,572,864
    float* bcat = (float*)(w + 1573888);              // 6,144
    u16*   xf   = (u16*)(w + 1580032);                // 16,777,216
    u16*   qf   = (u16*)(w + 18357248);
    u16*   kf   = (u16*)(w + 35134464);
    u16*   vT   = (u16*)(w + 51911680);               // [512][16384]
    float* scA  = (float*)(w + 68688896);             // scores arena

    const size_t avail = ws_size > 68688896ull ? ws_size - 68688896ull : 0;
    const size_t perb = (size_t)S * S * 4;
    const int c = avail >= 8 * perb ? 8 : avail >= 4 * perb ? 4 : avail >= 2 * perb ? 2 : 1;

    dim3 blk(256);

    detect_k<<<1, 64, 0, stream>>>((const u16*)x, flag);
    cvt_x<<<8192, blk, 0, stream>>>(x, xf, flag);
    pack_w<<<dim3(512, 6), blk, 0, stream>>>(Wq, Wk, Wv, WT, flag);
    pack_bias<<<6, blk, 0, stream>>>(bq, bk, bv, bcat, flag);

    // fused q|k|v projection: [16384,512] x [512,1536]^T(packed WT)
    gemm_f16<2><<<dim3(12, 128, 1), blk, 0, stream>>>(
        xf, WT, nullptr, bcat, qf, kf, vT, flag,
        512, 512, 512, 0, 0, 0, 0, 0);

    for (int cb = 0; cb < B_N; cb += c) {
        const size_t off = (size_t)cb * SD;
        // scores = q k^T (fp32)
        gemm_f16<0><<<dim3(16, 16, c), blk, 0, stream>>>(
            qf + off, kf + off, scA, nullptr, nullptr, nullptr, nullptr, flag,
            512, 512, 512, S, SD, SD, (long)S * S, 0);
        softmax_k<<<c * S, blk, 0, stream>>>(scA);
        // out = P @ v via vT rows; P fp16 over fp32 rows (lda = 2S)
        gemm_f16<1><<<dim3(4, 16, c), blk, 0, stream>>>(
            (const u16*)scA, vT + (size_t)cb * S, d_out, nullptr,
            nullptr, nullptr, nullptr, flag,
            S, 2 * S, B_N * S, D, 2ll * S * S, S, SD, (long)cb * SD);
    }
}